// Round 4
// baseline (184.624 us; speedup 1.0000x reference)
//
#include <hip/hip_runtime.h>
#include <cstddef>

// Problem constants
constexpr int B_ = 4, H_ = 96, W_ = 96, C_ = 192, QKVC = 576;
constexpr int NPIX = B_ * H_ * W_;           // 36864
// exp(s*SCALE) = 2^(s*C2), C2 = 32^-0.5 * log2(e)
constexpr float C2 = 0.25503486208385085f;

typedef __attribute__((ext_vector_type(8))) short bf16x8;
typedef __attribute__((ext_vector_type(4))) float f32x4;
typedef unsigned short ushort_t;

__device__ __forceinline__ unsigned short f2bf(float f) {
    unsigned int u = __builtin_bit_cast(unsigned int, f);
    u += 0x7fffu + ((u >> 16) & 1u);       // round-to-nearest-even
    return (unsigned short)(u >> 16);
}
__device__ __forceinline__ float bf2f(unsigned short h) {
    unsigned int u = ((unsigned int)h) << 16;
    return __builtin_bit_cast(float, u);
}
__device__ __forceinline__ unsigned int pack2(unsigned short a, unsigned short b) {
    return (unsigned int)a | ((unsigned int)b << 16);   // a -> low half
}
__device__ __forceinline__ float fexp2(float x) {
#if __has_builtin(__builtin_amdgcn_exp2f)
    return __builtin_amdgcn_exp2f(x);
#else
    return __expf(x * 0.6931471805599453f);
#endif
}

// ---------------------------------------------------------------------------
// convert_x: fp32 -> bf16
// ---------------------------------------------------------------------------
__global__ __launch_bounds__(256) void convert_x_kernel(
    const float* __restrict__ x, ushort_t* __restrict__ xh, int n4)
{
    int i = blockIdx.x * 256 + threadIdx.x;
    if (i >= n4) return;
    float4 v = ((const float4*)x)[i];
    uint2 p;
    p.x = pack2(f2bf(v.x), f2bf(v.y));
    p.y = pack2(f2bf(v.z), f2bf(v.w));
    ((uint2*)xh)[i] = p;
}

// ---------------------------------------------------------------------------
// convert_w: w_qkv -> wqt[576][192] bf16; w_proj -> wpt_h/wpt_l split bf16.
// ---------------------------------------------------------------------------
__global__ __launch_bounds__(256) void convert_w_kernel(
    const float* __restrict__ w_qkv, const float* __restrict__ w_proj,
    ushort_t* __restrict__ wqt, ushort_t* __restrict__ wpt_h,
    ushort_t* __restrict__ wpt_l)
{
    int idx = blockIdx.x * 256 + threadIdx.x;
    if (idx < 576 * 192) {
        int n = idx / 192, k = idx - n * 192;
        wqt[idx] = f2bf(w_qkv[(size_t)k * 576 + n]);
    } else {
        int i2 = idx - 576 * 192;
        if (i2 < 192 * 192) {
            int n = i2 / 192, k = i2 - n * 192;
            float v = w_proj[(size_t)k * 192 + n];
            unsigned short h = f2bf(v);
            wpt_h[i2] = h;
            wpt_l[i2] = f2bf(v - bf2f(h));
        }
    }
}

// ---------------------------------------------------------------------------
// MFMA bf16 GEMM, tile 64xNTx64. A bf16 [M][K], B pre-transposed Bt[n][k].
// BSPLIT: 2 passes A*(Bh+Bl). OUTBF: bf16 C. VT: write the v-channels
// (local col 128..191, requires NT=192) ONLY to vT (dim-major), packed as
// one 8B store per fragment (4 consecutive jj at fixed dd).
// Grid is XCD-swizzled (gridDim.x must be a multiple of 8).
// ---------------------------------------------------------------------------
template<bool BSPLIT, bool OUTBF, bool VT, int NT>
__global__ __launch_bounds__(256) void gemm_mfma2_kernel(
    const ushort_t* __restrict__ A,
    const ushort_t* __restrict__ Bt_h, const ushort_t* __restrict__ Bt_l,
    const float* __restrict__ bias, void* __restrict__ Cout,
    ushort_t* __restrict__ vTout, int M, int N, int K)
{
    constexpr int NPB = BSPLIT ? 2 : 1;
    constexpr int NI = NT / 32;            // 16-wide frags per wave (n-dim)
    __shared__ __align__(16) ushort_t As[8 * 64 * 8];
    __shared__ __align__(16) ushort_t Bs[NPB][8 * NT * 8];

    const int tid = threadIdx.x;
    const int lane = tid & 63;
    const int w = tid >> 6;
    const int wm = (w & 1) * 32;
    const int wn = (w >> 1) * (NT / 2);
    const int fm = lane & 15;
    const int fq = lane >> 4;

    // bijective XCD-contiguity swizzle
    const int phys = blockIdx.x;
    const int bid = (phys & 7) * (int)(gridDim.x >> 3) + (phys >> 3);
    const int ntiles = N / NT;
    const int m0 = (bid / ntiles) * 64;
    const int n0 = (bid % ntiles) * NT;

    f32x4 acc[2][NI];
    #pragma unroll
    for (int mi = 0; mi < 2; ++mi)
        #pragma unroll
        for (int ni = 0; ni < NI; ++ni)
            acc[mi][ni] = (f32x4){0.f, 0.f, 0.f, 0.f};

    for (int k0 = 0; k0 < K; k0 += 64) {
        __syncthreads();
        #pragma unroll
        for (int it = 0; it < 2; ++it) {
            int idx = it * 256 + tid;
            int m = idx >> 3, kc = idx & 7;
            uint4 v = *(const uint4*)(A + (size_t)(m0 + m) * K + k0 + kc * 8);
            *(uint4*)(&As[0] + (kc * 64 + (m ^ kc)) * 8) = v;
        }
        #pragma unroll
        for (int it = 0; it < NI; ++it) {
            int idx = it * 256 + tid;
            int n = idx >> 3, kc = idx & 7;
            int phys_g = kc * NT + (n ^ kc);
            *(uint4*)(&Bs[0][0] + phys_g * 8) =
                *(const uint4*)(Bt_h + (size_t)(n0 + n) * K + k0 + kc * 8);
            if constexpr (BSPLIT)
                *(uint4*)(&Bs[NPB - 1][0] + phys_g * 8) =
                    *(const uint4*)(Bt_l + (size_t)(n0 + n) * K + k0 + kc * 8);
        }
        __syncthreads();

        #pragma unroll
        for (int kt2 = 0; kt2 < 2; ++kt2) {
            const int kc = kt2 * 4 + fq;
            bf16x8 ah[2], bh[NI];
            #pragma unroll
            for (int mi = 0; mi < 2; ++mi)
                ah[mi] = *(const bf16x8*)(&As[0] + (kc * 64 + ((wm + mi * 16 + fm) ^ kc)) * 8);
            #pragma unroll
            for (int ni = 0; ni < NI; ++ni)
                bh[ni] = *(const bf16x8*)(&Bs[0][0] + (kc * NT + ((wn + ni * 16 + fm) ^ kc)) * 8);
            #pragma unroll
            for (int mi = 0; mi < 2; ++mi)
                #pragma unroll
                for (int ni = 0; ni < NI; ++ni)
                    acc[mi][ni] = __builtin_amdgcn_mfma_f32_16x16x32_bf16(
                        ah[mi], bh[ni], acc[mi][ni], 0, 0, 0);
            if constexpr (BSPLIT) {
                bf16x8 bl[NI];
                #pragma unroll
                for (int ni = 0; ni < NI; ++ni)
                    bl[ni] = *(const bf16x8*)(&Bs[NPB - 1][0] + (kc * NT + ((wn + ni * 16 + fm) ^ kc)) * 8);
                #pragma unroll
                for (int mi = 0; mi < 2; ++mi)
                    #pragma unroll
                    for (int ni = 0; ni < NI; ++ni)
                        acc[mi][ni] = __builtin_amdgcn_mfma_f32_16x16x32_bf16(
                            ah[mi], bl[ni], acc[mi][ni], 0, 0, 0);
            }
        }
    }

    // epilogue: C/D col=lane&15, row=fq*4+reg
    #pragma unroll
    for (int ni = 0; ni < NI; ++ni) {
        const int lcol = wn + ni * 16 + fm;
        const int col = n0 + lcol;
        const float bv = bias[col];
        const int vl = lcol - 128;               // v-channel index (if >=0)
        #pragma unroll
        for (int mi = 0; mi < 2; ++mi) {
            const int rbase = m0 + wm + mi * 16 + fq * 4;
            if constexpr (VT) {
                if (vl >= 0) {
                    // 4 r-values are 4 consecutive jj at fixed dd: one 8B store.
                    int bb = rbase / 9216;
                    int rem = rbase - bb * 9216;
                    int ii = rem / 96;
                    int jj = rem - ii * 96;
                    int hh = vl >> 5, dd = vl & 31;
                    unsigned long long pk =
                          (unsigned long long)f2bf(acc[mi][ni][0] + bv)
                        | ((unsigned long long)f2bf(acc[mi][ni][1] + bv) << 16)
                        | ((unsigned long long)f2bf(acc[mi][ni][2] + bv) << 32)
                        | ((unsigned long long)f2bf(acc[mi][ni][3] + bv) << 48);
                    *(unsigned long long*)(vTout
                        + ((size_t)((bb * 96 + ii) * 6) + (n0 / 192) * 2 + hh) * 3072
                        + (size_t)dd * 96 + jj) = pk;
                    continue;                    // v never read from qkvh
                }
            }
            #pragma unroll
            for (int r = 0; r < 4; ++r) {
                float val = acc[mi][ni][r] + bv;
                if constexpr (OUTBF)
                    ((ushort_t*)Cout)[(size_t)(rbase + r) * N + col] = f2bf(val);
                else
                    ((float*)Cout)[(size_t)(rbase + r) * N + col] = val;
            }
        }
    }
}

// ---------------------------------------------------------------------------
// Neighborhood attention v6b — swapped-QK^T, fully in-register, zero LDS,
// zero barriers. All primitives individually HW-verified: fragment layout
// conventions identical to the passing GEMM above; bf16 pack via f2bf/pack2
// (NOT v_cvt_pk asm — that was R2's sole unverified primitive and the prime
// suspect for its numerator misrouting); exp2-bias mask (verified R3);
// XCD-bijective swizzle (verified R1/R3).
//
// Block = 128 threads = 2 independent waves; each wave owns one 16-pixel
// chunk of row i for one (g,h,b). Grid 6912 = 8*864.
// S^T = mfma(A=K, B=Q): C-layout (verified) puts j = lane&15 (fm) and
// window-col offset = fq*4+r in regs. The 8 per-lane P values sit at exactly
// the A-frag k-slots (k = fq*8+e, e<4 -> s0[r=e], e>=4 -> s1[r=e-4]) under
// the column enumeration c(8q+e) = cb + (e<4 ? q*4+e : 16+q*4+e-4).
// V's B-frag matches with two 8B loads per lane from dim-major vT.
// l is per-lane (j fixed per lane): 2 shfl_xor + shfl broadcast at the end.
// ---------------------------------------------------------------------------
__global__ __launch_bounds__(128, 4) void na2d_kernel(
    const ushort_t* __restrict__ qkv, const ushort_t* __restrict__ vT,
    ushort_t* __restrict__ attn)
{
    // bijective XCD-contiguity swizzle (6912 = 8 * 864)
    int phys = blockIdx.x;
    int idx = (phys & 7) * 864 + (phys >> 3);

    const int c2 = idx % 3; idx /= 3;      // chunk-pair
    const int g  = idx % 3; idx /= 3;
    const int h  = idx & 1; idx >>= 1;
    const int i  = idx % 96;
    const int b  = idx / 96;

    const int K = 7 + 2 * g, cc = K >> 1;
    int si = i - cc; if (si < 0) si = 0; if (si > H_ - K) si = H_ - K;

    const int tid = threadIdx.x;
    const int w = tid >> 6, lane = tid & 63;
    const int fm = lane & 15, fq = lane >> 4;
    const int pixbase = (c2 * 2 + w) * 16;

    int cb = (pixbase - cc) & ~7;          // aligned union-window base
    if (cb < 0) cb = 0; if (cb > 64) cb = 64;

    // per-lane softmax mask -> exp2 bias (loop-invariant); lane's q-pixel j=fm
    const int jlane = pixbase + fm;
    int sjl = jlane - cc; if (sjl < 0) sjl = 0; if (sjl > W_ - K) sjl = W_ - K;
    float b0[4], b1[4];
    #pragma unroll
    for (int r = 0; r < 4; ++r) {
        b0[r] = ((unsigned)(cb + fq * 4 + r - sjl)      < (unsigned)K) ? 0.f : -1e30f;
        b1[r] = ((unsigned)(cb + 16 + fq * 4 + r - sjl) < (unsigned)K) ? 0.f : -1e30f;
    }

    // Q B-frag: pixel j = pixbase+fm, dims fq*8..+8 (loop-invariant)
    const size_t rowstride = (size_t)W_ * QKVC;    // ushorts per image row
    const bf16x8 qfrag = *(const bf16x8*)(
        qkv + (size_t)(b * H_ + i) * rowstride + (size_t)jlane * QKVC
        + g * 192 + h * 32 + fq * 8);

    // K A-frag pointers: pixel c = cb+fm (+16), dims fq*8..+8
    const ushort_t* kp0 = qkv + (size_t)(b * H_ + si) * rowstride
        + (size_t)(cb + fm) * QKVC + g * 192 + 64 + h * 32 + fq * 8;
    const ushort_t* kp1 = kp0 + (size_t)16 * QKVC;
    // V B-frag pointer: vT[slice][d=fm][cb + fq*4]; 4x 8B loads via offsets
    const size_t vslice = ((size_t)((b * H_ + si) * 6) + g * 2 + h) * 3072;
    const ushort_t* vp = vT + vslice + (size_t)fm * 96 + cb + fq * 4;

    f32x4 y0 = {0.f, 0.f, 0.f, 0.f}, y1 = {0.f, 0.f, 0.f, 0.f};
    float lsum = 0.f;

    bf16x8 kf0 = *(const bf16x8*)kp0;
    bf16x8 kf1 = *(const bf16x8*)kp1;
    uint2 va = *(const uint2*)(vp);
    uint2 vb = *(const uint2*)(vp + 16);
    uint2 vc = *(const uint2*)(vp + 1536);
    uint2 vd = *(const uint2*)(vp + 1552);

    for (int t = 0; t < K; ++t) {
        const bf16x8 ck0 = kf0, ck1 = kf1;
        const bf16x8 cv0 = __builtin_bit_cast(bf16x8, (uint4){va.x, va.y, vb.x, vb.y});
        const bf16x8 cv1 = __builtin_bit_cast(bf16x8, (uint4){vc.x, vc.y, vd.x, vd.y});
        if (t + 1 < K) {                   // register prefetch of next row
            kp0 += rowstride; kp1 += rowstride; vp += 18432;
            kf0 = *(const bf16x8*)kp0;
            kf1 = *(const bf16x8*)kp1;
            va = *(const uint2*)(vp);
            vb = *(const uint2*)(vp + 16);
            vc = *(const uint2*)(vp + 1536);
            vd = *(const uint2*)(vp + 1552);
        }

        // ---- S^T = K·Q^T: lane holds j=fm, c-offsets fq*4+r / 16+fq*4+r ----
        f32x4 s0 = __builtin_amdgcn_mfma_f32_16x16x32_bf16(
            ck0, qfrag, (f32x4){0.f, 0.f, 0.f, 0.f}, 0, 0, 0);
        f32x4 s1 = __builtin_amdgcn_mfma_f32_16x16x32_bf16(
            ck1, qfrag, (f32x4){0.f, 0.f, 0.f, 0.f}, 0, 0, 0);

        // ---- e = 2^(s*C2 + bias); manual RTNE pack (verified primitive) ----
        unsigned short p00 = f2bf(fexp2(fmaf(s0[0], C2, b0[0])));
        unsigned short p01 = f2bf(fexp2(fmaf(s0[1], C2, b0[1])));
        unsigned short p02 = f2bf(fexp2(fmaf(s0[2], C2, b0[2])));
        unsigned short p03 = f2bf(fexp2(fmaf(s0[3], C2, b0[3])));
        unsigned short p10 = f2bf(fexp2(fmaf(s1[0], C2, b1[0])));
        unsigned short p11 = f2bf(fexp2(fmaf(s1[1], C2, b1[1])));
        unsigned short p12 = f2bf(fexp2(fmaf(s1[2], C2, b1[2])));
        unsigned short p13 = f2bf(fexp2(fmaf(s1[3], C2, b1[3])));
        // denominator from the SAME rounded values as the numerator
        lsum += (bf2f(p00) + bf2f(p01)) + (bf2f(p02) + bf2f(p03))
              + (bf2f(p10) + bf2f(p11)) + (bf2f(p12) + bf2f(p13));
        // A-frag k-slot order: e=0..3 -> s0[e] (lo first), e=4..7 -> s1[e-4]
        const bf16x8 pa = __builtin_bit_cast(bf16x8, (uint4){
            pack2(p00, p01), pack2(p02, p03),
            pack2(p10, p11), pack2(p12, p13)});

        // ---- y += P·V (d-lo, d-hi tiles) ----
        y0 = __builtin_amdgcn_mfma_f32_16x16x32_bf16(pa, cv0, y0, 0, 0, 0);
        y1 = __builtin_amdgcn_mfma_f32_16x16x32_bf16(pa, cv1, y1, 0, 0, 0);
    }

    // ---- reduce l across the 4 fq-groups, broadcast per output row ----
    lsum += __shfl_xor(lsum, 16);
    lsum += __shfl_xor(lsum, 32);          // l[j=fm], uniform over fq

    #pragma unroll
    for (int r = 0; r < 4; ++r) {
        const float l = __shfl(lsum, fq * 4 + r);   // lane fq*4+r has fm=fq*4+r
        const float inv = 1.f / l;
        const int j = pixbase + fq * 4 + r;
        const size_t o = (size_t)((b * H_ + i) * W_ + j) * C_ + g * 64 + h * 32 + fm;
        attn[o]      = f2bf(y0[r] * inv);
        attn[o + 16] = f2bf(y1[r] * inv);
    }
}

// ---------------------------------------------------------------------------
extern "C" void kernel_launch(void* const* d_in, const int* in_sizes, int n_in,
                              void* d_out, int out_size, void* d_ws, size_t ws_size,
                              hipStream_t stream)
{
    const float* x      = (const float*)d_in[0];
    const float* w_qkv  = (const float*)d_in[1];
    const float* b_qkv  = (const float*)d_in[2];
    const float* w_proj = (const float*)d_in[3];
    const float* b_proj = (const float*)d_in[4];
    float* out = (float*)d_out;

    // Workspace: [qkvh 42.5MB][xh/attn bf16 14.2MB aliased][weights][vT 14.2MB]
    char* ws = (char*)d_ws;
    ushort_t* qkvh  = (ushort_t*)ws;
    char*     reg1  = ws + (size_t)NPIX * QKVC * 2;
    ushort_t* xh    = (ushort_t*)reg1;            // dead after GEMM1
    ushort_t* attn  = (ushort_t*)reg1;            // aliases xh
    char*     wbase = reg1 + (size_t)NPIX * C_ * 2;
    ushort_t* wqt   = (ushort_t*)wbase;
    ushort_t* wpt_h = (ushort_t*)(wbase + 576 * 192 * 2);
    ushort_t* wpt_l = (ushort_t*)(wbase + 576 * 192 * 2 + 192 * 192 * 2);
    ushort_t* vT    = (ushort_t*)(wbase + 576 * 192 * 2 + 2 * 192 * 192 * 2);

    convert_x_kernel<<<(NPIX * C_ / 4 + 255) / 256, 256, 0, stream>>>(
        x, xh, NPIX * C_ / 4);
    convert_w_kernel<<<(576 * 192 + 192 * 192 + 255) / 256, 256, 0, stream>>>(
        w_qkv, w_proj, wqt, wpt_h, wpt_l);

    // 1) qkv = x @ w_qkv + b_qkv (bf16 out, q/k only) + transposed v copy (vT)
    //    grid 1728 = 8 * 216 (XCD-swizzled)
    gemm_mfma2_kernel<false, true, true, 192><<<(NPIX / 64) * (QKVC / 192), 256, 0, stream>>>(
        xh, wqt, nullptr, b_qkv, qkvh, vT, NPIX, QKVC, C_);

    // 2) neighborhood attention (in-register, zero-LDS, zero-barrier)
    na2d_kernel<<<6912, 128, 0, stream>>>(qkvh, vT, attn);

    // 3) out = attn @ w_proj + b_proj (A bf16, B split-bf16 2-pass, N-tile 96)
    //    grid 1152 = 8 * 144 (XCD-swizzled)
    gemm_mfma2_kernel<true, false, false, 96><<<(NPIX / 64) * (C_ / 96), 256, 0, stream>>>(
        attn, wpt_h, wpt_l, b_proj, out, nullptr, NPIX, C_, C_);
}

// Round 5
// 155.456 us; speedup vs baseline: 1.1876x; 1.1876x over previous
//
#include <hip/hip_runtime.h>
#include <cstddef>

// Problem constants
constexpr int B_ = 4, H_ = 96, W_ = 96, C_ = 192, QKVC = 576;
constexpr int NPIX = B_ * H_ * W_;           // 36864
// exp(s*SCALE) = 2^(s*C2), C2 = 32^-0.5 * log2(e)
constexpr float C2 = 0.25503486208385085f;

typedef __attribute__((ext_vector_type(8))) short bf16x8;
typedef __attribute__((ext_vector_type(4))) float f32x4;
typedef unsigned short ushort_t;

__device__ __forceinline__ unsigned short f2bf(float f) {
    unsigned int u = __builtin_bit_cast(unsigned int, f);
    u += 0x7fffu + ((u >> 16) & 1u);       // round-to-nearest-even
    return (unsigned short)(u >> 16);
}
__device__ __forceinline__ float bf2f(unsigned short h) {
    unsigned int u = ((unsigned int)h) << 16;
    return __builtin_bit_cast(float, u);
}
__device__ __forceinline__ unsigned int pack2(unsigned short a, unsigned short b) {
    return (unsigned int)a | ((unsigned int)b << 16);   // a -> low half
}
__device__ __forceinline__ float fexp2(float x) {
#if __has_builtin(__builtin_amdgcn_exp2f)
    return __builtin_amdgcn_exp2f(x);
#else
    return __expf(x * 0.6931471805599453f);
#endif
}

// ---------------------------------------------------------------------------
// convert_x: fp32 -> bf16
// ---------------------------------------------------------------------------
__global__ __launch_bounds__(256) void convert_x_kernel(
    const float* __restrict__ x, ushort_t* __restrict__ xh, int n4)
{
    int i = blockIdx.x * 256 + threadIdx.x;
    if (i >= n4) return;
    float4 v = ((const float4*)x)[i];
    uint2 p;
    p.x = pack2(f2bf(v.x), f2bf(v.y));
    p.y = pack2(f2bf(v.z), f2bf(v.w));
    ((uint2*)xh)[i] = p;
}

// ---------------------------------------------------------------------------
// convert_w: w_qkv -> wqt[576][192] bf16; w_proj -> wpt_h/wpt_l split bf16.
// ---------------------------------------------------------------------------
__global__ __launch_bounds__(256) void convert_w_kernel(
    const float* __restrict__ w_qkv, const float* __restrict__ w_proj,
    ushort_t* __restrict__ wqt, ushort_t* __restrict__ wpt_h,
    ushort_t* __restrict__ wpt_l)
{
    int idx = blockIdx.x * 256 + threadIdx.x;
    if (idx < 576 * 192) {
        int n = idx / 192, k = idx - n * 192;
        wqt[idx] = f2bf(w_qkv[(size_t)k * 576 + n]);
    } else {
        int i2 = idx - 576 * 192;
        if (i2 < 192 * 192) {
            int n = i2 / 192, k = i2 - n * 192;
            float v = w_proj[(size_t)k * 192 + n];
            unsigned short h = f2bf(v);
            wpt_h[i2] = h;
            wpt_l[i2] = f2bf(v - bf2f(h));
        }
    }
}

// ---------------------------------------------------------------------------
// MFMA bf16 GEMM, tile 64xNTx64. A bf16 [M][K], B pre-transposed Bt[n][k].
// BSPLIT: 2 passes A*(Bh+Bl). OUTBF: bf16 C. VT: write the v-channels
// (local col 128..191, requires NT=192) ONLY to vT (dim-major), packed as
// one 8B store per fragment (4 consecutive jj at fixed dd).
// Grid is XCD-swizzled (gridDim.x must be a multiple of 8).
// ---------------------------------------------------------------------------
template<bool BSPLIT, bool OUTBF, bool VT, int NT>
__global__ __launch_bounds__(256) void gemm_mfma2_kernel(
    const ushort_t* __restrict__ A,
    const ushort_t* __restrict__ Bt_h, const ushort_t* __restrict__ Bt_l,
    const float* __restrict__ bias, void* __restrict__ Cout,
    ushort_t* __restrict__ vTout, int M, int N, int K)
{
    constexpr int NPB = BSPLIT ? 2 : 1;
    constexpr int NI = NT / 32;            // 16-wide frags per wave (n-dim)
    __shared__ __align__(16) ushort_t As[8 * 64 * 8];
    __shared__ __align__(16) ushort_t Bs[NPB][8 * NT * 8];

    const int tid = threadIdx.x;
    const int lane = tid & 63;
    const int w = tid >> 6;
    const int wm = (w & 1) * 32;
    const int wn = (w >> 1) * (NT / 2);
    const int fm = lane & 15;
    const int fq = lane >> 4;

    // bijective XCD-contiguity swizzle
    const int phys = blockIdx.x;
    const int bid = (phys & 7) * (int)(gridDim.x >> 3) + (phys >> 3);
    const int ntiles = N / NT;
    const int m0 = (bid / ntiles) * 64;
    const int n0 = (bid % ntiles) * NT;

    f32x4 acc[2][NI];
    #pragma unroll
    for (int mi = 0; mi < 2; ++mi)
        #pragma unroll
        for (int ni = 0; ni < NI; ++ni)
            acc[mi][ni] = (f32x4){0.f, 0.f, 0.f, 0.f};

    for (int k0 = 0; k0 < K; k0 += 64) {
        __syncthreads();
        #pragma unroll
        for (int it = 0; it < 2; ++it) {
            int idx = it * 256 + tid;
            int m = idx >> 3, kc = idx & 7;
            uint4 v = *(const uint4*)(A + (size_t)(m0 + m) * K + k0 + kc * 8);
            *(uint4*)(&As[0] + (kc * 64 + (m ^ kc)) * 8) = v;
        }
        #pragma unroll
        for (int it = 0; it < NI; ++it) {
            int idx = it * 256 + tid;
            int n = idx >> 3, kc = idx & 7;
            int phys_g = kc * NT + (n ^ kc);
            *(uint4*)(&Bs[0][0] + phys_g * 8) =
                *(const uint4*)(Bt_h + (size_t)(n0 + n) * K + k0 + kc * 8);
            if constexpr (BSPLIT)
                *(uint4*)(&Bs[NPB - 1][0] + phys_g * 8) =
                    *(const uint4*)(Bt_l + (size_t)(n0 + n) * K + k0 + kc * 8);
        }
        __syncthreads();

        #pragma unroll
        for (int kt2 = 0; kt2 < 2; ++kt2) {
            const int kc = kt2 * 4 + fq;
            bf16x8 ah[2], bh[NI];
            #pragma unroll
            for (int mi = 0; mi < 2; ++mi)
                ah[mi] = *(const bf16x8*)(&As[0] + (kc * 64 + ((wm + mi * 16 + fm) ^ kc)) * 8);
            #pragma unroll
            for (int ni = 0; ni < NI; ++ni)
                bh[ni] = *(const bf16x8*)(&Bs[0][0] + (kc * NT + ((wn + ni * 16 + fm) ^ kc)) * 8);
            #pragma unroll
            for (int mi = 0; mi < 2; ++mi)
                #pragma unroll
                for (int ni = 0; ni < NI; ++ni)
                    acc[mi][ni] = __builtin_amdgcn_mfma_f32_16x16x32_bf16(
                        ah[mi], bh[ni], acc[mi][ni], 0, 0, 0);
            if constexpr (BSPLIT) {
                bf16x8 bl[NI];
                #pragma unroll
                for (int ni = 0; ni < NI; ++ni)
                    bl[ni] = *(const bf16x8*)(&Bs[NPB - 1][0] + (kc * NT + ((wn + ni * 16 + fm) ^ kc)) * 8);
                #pragma unroll
                for (int mi = 0; mi < 2; ++mi)
                    #pragma unroll
                    for (int ni = 0; ni < NI; ++ni)
                        acc[mi][ni] = __builtin_amdgcn_mfma_f32_16x16x32_bf16(
                            ah[mi], bl[ni], acc[mi][ni], 0, 0, 0);
            }
        }
    }

    // epilogue: C/D col=lane&15, row=fq*4+reg
    #pragma unroll
    for (int ni = 0; ni < NI; ++ni) {
        const int lcol = wn + ni * 16 + fm;
        const int col = n0 + lcol;
        const float bv = bias[col];
        const int vl = lcol - 128;               // v-channel index (if >=0)
        #pragma unroll
        for (int mi = 0; mi < 2; ++mi) {
            const int rbase = m0 + wm + mi * 16 + fq * 4;
            if constexpr (VT) {
                if (vl >= 0) {
                    // 4 r-values are 4 consecutive jj at fixed dd: one 8B store.
                    int bb = rbase / 9216;
                    int rem = rbase - bb * 9216;
                    int ii = rem / 96;
                    int jj = rem - ii * 96;
                    int hh = vl >> 5, dd = vl & 31;
                    unsigned long long pk =
                          (unsigned long long)f2bf(acc[mi][ni][0] + bv)
                        | ((unsigned long long)f2bf(acc[mi][ni][1] + bv) << 16)
                        | ((unsigned long long)f2bf(acc[mi][ni][2] + bv) << 32)
                        | ((unsigned long long)f2bf(acc[mi][ni][3] + bv) << 48);
                    *(unsigned long long*)(vTout
                        + ((size_t)((bb * 96 + ii) * 6) + (n0 / 192) * 2 + hh) * 3072
                        + (size_t)dd * 96 + jj) = pk;
                    continue;                    // v never read from qkvh
                }
            }
            #pragma unroll
            for (int r = 0; r < 4; ++r) {
                float val = acc[mi][ni][r] + bv;
                if constexpr (OUTBF)
                    ((ushort_t*)Cout)[(size_t)(rbase + r) * N + col] = f2bf(val);
                else
                    ((float*)Cout)[(size_t)(rbase + r) * N + col] = val;
            }
        }
    }
}

// ---------------------------------------------------------------------------
// Neighborhood attention v7 — hybrid of the two verified structures:
//   * v4b's cooperative coalesced K/Vt staging (tid*16B loads, double-
//     buffered LDS, 6 waves / 2304 blocks) — request-efficient memory path.
//   * v6b's swapped S^T = mfma(A=K, B=Q) with in-register P (exp2-bias mask,
//     f2bf/pack2 RTNE pack, per-lane lsum) — no Pb LDS round-trip.
// The K fragment bytes are identical to v4b's (A- and B-frags share the same
// per-lane data layout); only operand order and C-interpretation change.
// V B-frags come from Vtb via 4x ds_read_b64 (8B-aligned).
// Per iteration vs v4b: ~130 fewer VALU ops, no 8x ds_write_b16 + ds_read_b128
// serial P chain. Per iteration vs v6b: ~6x fewer L2 requests.
// ---------------------------------------------------------------------------
__global__ __launch_bounds__(384, 5) void na2d_kernel(
    const ushort_t* __restrict__ qkv, const ushort_t* __restrict__ vT,
    ushort_t* __restrict__ attn)
{
    __shared__ ushort_t Kb[2][96 * 40];    // [col][pad40], chunk-XOR swizzle
    __shared__ ushort_t Vtb[2][32 * 104];  // [dim][pad104]

    // bijective XCD-contiguity swizzle (2304 = 8 * 288)
    int phys = blockIdx.x;
    int idx = (phys & 7) * 288 + (phys >> 3);

    const int g = idx % 3; idx /= 3;       // g fastest: XCD load balance
    const int h = idx & 1; idx >>= 1;
    const int i = idx % 96;
    const int b = idx / 96;

    const int K = 7 + 2 * g, cc = K >> 1;
    int si = i - cc; if (si < 0) si = 0; if (si > H_ - K) si = H_ - K;

    const int tid = threadIdx.x;
    const int w = tid >> 6, lane = tid & 63;
    const int fm = lane & 15, fq = lane >> 4;
    const int pixbase = w * 16;

    int cb = (pixbase - cc) & ~7;          // aligned union-window base
    if (cb < 0) cb = 0; if (cb > 64) cb = 64;
    const int col0 = cb + fm, col1 = cb + 16 + fm;

    // per-lane softmax mask -> exp2 bias (v6b, verified); lane's q-pixel j=fm
    const int jlane = pixbase + fm;
    int sjl = jlane - cc; if (sjl < 0) sjl = 0; if (sjl > W_ - K) sjl = W_ - K;
    float b0[4], b1[4];
    #pragma unroll
    for (int r = 0; r < 4; ++r) {
        b0[r] = ((unsigned)(cb + fq * 4 + r - sjl)      < (unsigned)K) ? 0.f : -1e30f;
        b1[r] = ((unsigned)(cb + 16 + fq * 4 + r - sjl) < (unsigned)K) ? 0.f : -1e30f;
    }

    // Q B-frag: pixel j=pixbase+fm, dims fq*8..+8 (loop-invariant)
    const size_t rowstride = (size_t)W_ * QKVC;    // ushorts per image row
    const bf16x8 qfrag = *(const bf16x8*)(
        qkv + (size_t)(b * H_ + i) * rowstride + (size_t)jlane * QKVC
        + g * 192 + h * 32 + fq * 8);

    // staging maps (coalesced: addr = base + tid*16B for both) — v4b verified
    const int scol = tid >> 2, sch = tid & 3;
    const size_t kgoff = (size_t)scol * QKVC + g * 192 + 64 + h * 32 + sch * 8;
    const int klds = scol * 40 + ((sch ^ (scol & 3)) << 3);
    const int vd = tid / 12, vc8 = tid - vd * 12;
    const int vlds = vd * 104 + vc8 * 8;
    const size_t vslice = ((size_t)((b * H_ + si) * 6) + g * 2 + h) * 3072;

    f32x4 y0 = {0.f, 0.f, 0.f, 0.f}, y1 = {0.f, 0.f, 0.f, 0.f};
    float lsum = 0.f;

    uint4 kv = *(const uint4*)(qkv + (size_t)(b * H_ + si) * rowstride + kgoff);
    uint4 vv = *(const uint4*)(vT + vslice + (size_t)tid * 8);

    for (int t = 0; t < K; ++t) {
        *(uint4*)&Kb[t & 1][klds] = kv;
        *(uint4*)&Vtb[t & 1][vlds] = vv;
        if (t + 1 < K) {
            kv = *(const uint4*)(qkv + (size_t)(b * H_ + si + t + 1) * rowstride + kgoff);
            vv = *(const uint4*)(vT + vslice + (size_t)(t + 1) * 18432 + (size_t)tid * 8);
        }
        __syncthreads();

        // ---- LDS fragment reads (K A-frag 2x b128; V B-frag 4x b64) ----
        bf16x8 kf0 = *(const bf16x8*)&Kb[t & 1][col0 * 40 + ((fq ^ (col0 & 3)) << 3)];
        bf16x8 kf1 = *(const bf16x8*)&Kb[t & 1][col1 * 40 + ((fq ^ (col1 & 3)) << 3)];
        const ushort_t* vb0 = &Vtb[t & 1][fm * 104 + cb + fq * 4];
        const ushort_t* vb1 = &Vtb[t & 1][(16 + fm) * 104 + cb + fq * 4];
        uint2 va0 = *(const uint2*)(vb0);
        uint2 va1 = *(const uint2*)(vb0 + 16);
        uint2 va2 = *(const uint2*)(vb1);
        uint2 va3 = *(const uint2*)(vb1 + 16);
        const bf16x8 cv0 = __builtin_bit_cast(bf16x8, (uint4){va0.x, va0.y, va1.x, va1.y});
        const bf16x8 cv1 = __builtin_bit_cast(bf16x8, (uint4){va2.x, va2.y, va3.x, va3.y});

        // ---- S^T = K·Q^T: lane holds j=fm, c-offsets fq*4+r / 16+fq*4+r ----
        f32x4 s0 = __builtin_amdgcn_mfma_f32_16x16x32_bf16(
            kf0, qfrag, (f32x4){0.f, 0.f, 0.f, 0.f}, 0, 0, 0);
        f32x4 s1 = __builtin_amdgcn_mfma_f32_16x16x32_bf16(
            kf1, qfrag, (f32x4){0.f, 0.f, 0.f, 0.f}, 0, 0, 0);

        // ---- e = 2^(s*C2 + bias); manual RTNE pack (v6b, verified) ----
        unsigned short p00 = f2bf(fexp2(fmaf(s0[0], C2, b0[0])));
        unsigned short p01 = f2bf(fexp2(fmaf(s0[1], C2, b0[1])));
        unsigned short p02 = f2bf(fexp2(fmaf(s0[2], C2, b0[2])));
        unsigned short p03 = f2bf(fexp2(fmaf(s0[3], C2, b0[3])));
        unsigned short p10 = f2bf(fexp2(fmaf(s1[0], C2, b1[0])));
        unsigned short p11 = f2bf(fexp2(fmaf(s1[1], C2, b1[1])));
        unsigned short p12 = f2bf(fexp2(fmaf(s1[2], C2, b1[2])));
        unsigned short p13 = f2bf(fexp2(fmaf(s1[3], C2, b1[3])));
        // denominator from the SAME rounded values as the numerator
        lsum += (bf2f(p00) + bf2f(p01)) + (bf2f(p02) + bf2f(p03))
              + (bf2f(p10) + bf2f(p11)) + (bf2f(p12) + bf2f(p13));
        // A-frag k-slot order: e=0..3 -> s0[e], e=4..7 -> s1[e-4]
        const bf16x8 pa = __builtin_bit_cast(bf16x8, (uint4){
            pack2(p00, p01), pack2(p02, p03),
            pack2(p10, p11), pack2(p12, p13)});

        // ---- y += P·V (d-lo, d-hi tiles) ----
        y0 = __builtin_amdgcn_mfma_f32_16x16x32_bf16(pa, cv0, y0, 0, 0, 0);
        y1 = __builtin_amdgcn_mfma_f32_16x16x32_bf16(pa, cv1, y1, 0, 0, 0);
    }

    // ---- reduce l across the 4 fq-groups, broadcast per output row ----
    lsum += __shfl_xor(lsum, 16);
    lsum += __shfl_xor(lsum, 32);          // l[j=fm], uniform over fq

    #pragma unroll
    for (int r = 0; r < 4; ++r) {
        const float l = __shfl(lsum, fq * 4 + r);   // lane fq*4+r has fm=fq*4+r
        const float inv = 1.f / l;
        const int j = pixbase + fq * 4 + r;
        const size_t o = (size_t)((b * H_ + i) * W_ + j) * C_ + g * 64 + h * 32 + fm;
        attn[o]      = f2bf(y0[r] * inv);
        attn[o + 16] = f2bf(y1[r] * inv);
    }
}

// ---------------------------------------------------------------------------
extern "C" void kernel_launch(void* const* d_in, const int* in_sizes, int n_in,
                              void* d_out, int out_size, void* d_ws, size_t ws_size,
                              hipStream_t stream)
{
    const float* x      = (const float*)d_in[0];
    const float* w_qkv  = (const float*)d_in[1];
    const float* b_qkv  = (const float*)d_in[2];
    const float* w_proj = (const float*)d_in[3];
    const float* b_proj = (const float*)d_in[4];
    float* out = (float*)d_out;

    // Workspace: [qkvh 42.5MB][xh/attn bf16 14.2MB aliased][weights][vT 14.2MB]
    char* ws = (char*)d_ws;
    ushort_t* qkvh  = (ushort_t*)ws;
    char*     reg1  = ws + (size_t)NPIX * QKVC * 2;
    ushort_t* xh    = (ushort_t*)reg1;            // dead after GEMM1
    ushort_t* attn  = (ushort_t*)reg1;            // aliases xh
    char*     wbase = reg1 + (size_t)NPIX * C_ * 2;
    ushort_t* wqt   = (ushort_t*)wbase;
    ushort_t* wpt_h = (ushort_t*)(wbase + 576 * 192 * 2);
    ushort_t* wpt_l = (ushort_t*)(wbase + 576 * 192 * 2 + 192 * 192 * 2);
    ushort_t* vT    = (ushort_t*)(wbase + 576 * 192 * 2 + 2 * 192 * 192 * 2);

    convert_x_kernel<<<(NPIX * C_ / 4 + 255) / 256, 256, 0, stream>>>(
        x, xh, NPIX * C_ / 4);
    convert_w_kernel<<<(576 * 192 + 192 * 192 + 255) / 256, 256, 0, stream>>>(
        w_qkv, w_proj, wqt, wpt_h, wpt_l);

    // 1) qkv = x @ w_qkv + b_qkv (bf16 out, q/k only) + transposed v copy (vT)
    //    grid 1728 = 8 * 216 (XCD-swizzled)
    gemm_mfma2_kernel<false, true, true, 192><<<(NPIX / 64) * (QKVC / 192), 256, 0, stream>>>(
        xh, wqt, nullptr, b_qkv, qkvh, vT, NPIX, QKVC, C_);

    // 2) neighborhood attention (hybrid: coop staging + in-register P)
    na2d_kernel<<<2304, 384, 0, stream>>>(qkvh, vT, attn);

    // 3) out = attn @ w_proj + b_proj (A bf16, B split-bf16 2-pass, N-tile 96)
    //    grid 1152 = 8 * 144 (XCD-swizzled)
    gemm_mfma2_kernel<true, false, false, 96><<<(NPIX / 64) * (C_ / 96), 256, 0, stream>>>(
        attn, wpt_h, wpt_l, b_proj, out, nullptr, NPIX, C_, C_);
}